// Round 9
// baseline (15.505 us; speedup 1.0000x reference)
//
#include <hip/hip_runtime.h>
#include <hip/hip_bf16.h>

#define S 1024
#define BLK 256    // 4 waves; 16 blocks/batch -> 1024 blocks, 4/CU

typedef float f32x2 __attribute__((ext_vector_type(2)));

// d = a + b (packed fp32, 2 ops / instruction)
__device__ __forceinline__ f32x2 pk_add(f32x2 a, f32x2 b) {
  f32x2 d;
  asm("v_pk_add_f32 %0, %1, %2" : "=v"(d) : "v"(a), "v"(b));
  return d;
}
// x = 1 - c*dp  (c negated via VOP3P neg modifiers)
__device__ __forceinline__ f32x2 pk_one_minus_mul(f32x2 c, f32x2 dp, f32x2 one2) {
  f32x2 x;
  asm("v_pk_fma_f32 %0, %1, %2, %3 neg_lo:[1,0,0] neg_hi:[1,0,0]"
      : "=v"(x) : "v"(c), "v"(dp), "v"(one2));
  return x;
}

// Two hinge terms (i, i+1) vs one j: labels integer-valued -> sign == med3-clamp.
// pj2n/lj2n are pre-negated broadcasts {-pj,-pj}/{-lj,-lj}.
__device__ __forceinline__ void pair2(f32x2 pi2, f32x2 li2,
                                      f32x2 pj2n, f32x2 lj2n,
                                      f32x2 one2, f32x2& acc2) {
  f32x2 dp2 = pk_add(pi2, pj2n);
  f32x2 dl2 = pk_add(li2, lj2n);
  f32x2 c2;
  c2.x = fminf(fmaxf(dl2.x, -1.0f), 1.0f);   // v_med3_f32
  c2.y = fminf(fmaxf(dl2.y, -1.0f), 1.0f);
  f32x2 x2 = pk_one_minus_mul(c2, dp2, one2);
  f32x2 t2;
  t2.x = fmaxf(x2.x, 0.0f);
  t2.y = fmaxf(x2.y, 0.0f);
  acc2 = pk_add(acc2, t2);
}

// Scalar predicated term for the diagonal row.
__device__ __forceinline__ float term1(float pi, float li, float pjn, float ljn) {
  float dp = pi + pjn;
  float dl = li + ljn;
  float c = fminf(fmaxf(dl, -1.0f), 1.0f);
  return fmaxf(fmaf(-c, dp, 1.0f), 0.0f);
}

// Staircase row R of group G (j in [256G,256G+256)): i in [gb+64R+off, +8).
// Reg R predicated (i<j), regs r>R full, regs r<R excluded. Static G,R.
template <int G, int R>
__device__ __forceinline__ void stair_t(const f32x2* p2, const f32x2* l2,
                                        int off, int lane,
                                        const f32x2 pj2n[4], const f32x2 lj2n[4],
                                        f32x2 one2, f32x2 acc2[4]) {
  const int gb = G * 256;
  const int i0 = gb + 64 * R + off;
  const int j = gb + 64 * R + lane;
#pragma unroll
  for (int t = 0; t < 4; ++t) {
    f32x2 pi2 = p2[(i0 >> 1) + t];
    f32x2 li2 = l2[(i0 >> 1) + t];
    const int i = i0 + 2 * t;
    {
      float ta = term1(pi2.x, li2.x, pj2n[R].x, lj2n[R].x);
      float tb = term1(pi2.y, li2.y, pj2n[R].x, lj2n[R].x);
      f32x2 t2;
      t2.x = (i     < j) ? ta : 0.0f;
      t2.y = (i + 1 < j) ? tb : 0.0f;
      acc2[R] = pk_add(acc2[R], t2);
    }
#pragma unroll
    for (int r = R + 1; r < 4; ++r)
      pair2(pi2, li2, pj2n[r], lj2n[r], one2, acc2[r]);
  }
}

// Group G body for slot s (0..31): uniform i in [s*8G, s*8G+8G) (below group)
// against all 4 j-regs, plus staircase row SR. Returns masked contribution.
template <int G>
__device__ __forceinline__ float group_body(const float* __restrict__ pS,
                                            const float* __restrict__ lS,
                                            const float* __restrict__ mS,
                                            int s, int SR, int lane) {
  const f32x2 one2 = {1.0f, 1.0f};
  f32x2 pj2n[4], lj2n[4];
  float mj[4];
#pragma unroll
  for (int r = 0; r < 4; ++r) {
    const int j = G * 256 + r * 64 + lane;
    const float pj = pS[j], lj = lS[j];
    pj2n[r].x = -pj; pj2n[r].y = -pj;
    lj2n[r].x = -lj; lj2n[r].y = -lj;
    mj[r] = mS[j];
  }
  f32x2 acc2[4] = {{0.f,0.f},{0.f,0.f},{0.f,0.f},{0.f,0.f}};

  const f32x2* p2 = (const f32x2*)pS;
  const f32x2* l2 = (const f32x2*)lS;

  if (G > 0) {
    const int f2lo = s * 4 * G;
#pragma unroll
    for (int t = 0; t < 4 * G; ++t) {
      f32x2 pi2 = p2[f2lo + t];
      f32x2 li2 = l2[f2lo + t];
#pragma unroll
      for (int r = 0; r < 4; ++r)
        pair2(pi2, li2, pj2n[r], lj2n[r], one2, acc2[r]);
    }
  }
  const int off = (s & 7) * 8;
  switch (SR) {  // wave-uniform
    case 0: stair_t<G,0>(p2, l2, off, lane, pj2n, lj2n, one2, acc2); break;
    case 1: stair_t<G,1>(p2, l2, off, lane, pj2n, lj2n, one2, acc2); break;
    case 2: stair_t<G,2>(p2, l2, off, lane, pj2n, lj2n, one2, acc2); break;
    default: stair_t<G,3>(p2, l2, off, lane, pj2n, lj2n, one2, acc2); break;
  }

  float w = 0.0f;
#pragma unroll
  for (int r = 0; r < 4; ++r)
    w = fmaf(acc2[r].x + acc2[r].y, mj[r], w);
  return w;
}

// Kernel 1: batch b = bid>>4, k = bid&15. P = k&1 -> group pair {P, 3-P};
// slot s = (k>>1)*4 + wave (0..31); hi-group stair row s>>3, lo-group 3-(s>>3).
__global__ __launch_bounds__(BLK) void rank_partial_kernel(
    const float* __restrict__ preds,
    const float* __restrict__ labels,
    float* __restrict__ partial) {
  const int bid = blockIdx.x;
  const int b = bid >> 4;
  const int k = bid & 15;

  __shared__ float pS[S];
  __shared__ float lS[S];
  __shared__ float mS[S];
  __shared__ float wsum[BLK / 64];

  const float* pr = preds + (size_t)b * S;
  const float* lr = labels + (size_t)b * S;
  {
    const float4 pv = ((const float4*)pr)[threadIdx.x];
    const float4 lv = ((const float4*)lr)[threadIdx.x];
    const float pm[4] = {pv.x, pv.y, pv.z, pv.w};
    const float lm[4] = {lv.x, lv.y, lv.z, lv.w};
#pragma unroll
    for (int e = 0; e < 4; ++e) {
      float m = (lm[e] != -1.0f) ? 1.0f : 0.0f;
      pS[threadIdx.x * 4 + e] = pm[e] * m;
      lS[threadIdx.x * 4 + e] = lm[e] * m;
      mS[threadIdx.x * 4 + e] = m;
    }
  }
  __syncthreads();

  const int wv = threadIdx.x >> 6;
  const int lane = threadIdx.x & 63;
  const int s = (k >> 1) * 4 + wv;
  const int R = s >> 3;

  float wacc;
  if (k & 1)
    wacc = group_body<1>(pS, lS, mS, s, 3 - R, lane)
         + group_body<2>(pS, lS, mS, s, R, lane);
  else
    wacc = group_body<0>(pS, lS, mS, s, 3 - R, lane)
         + group_body<3>(pS, lS, mS, s, R, lane);

  for (int offr = 32; offr > 0; offr >>= 1)
    wacc += __shfl_down(wacc, offr, 64);
  if (lane == 0) wsum[wv] = wacc;
  __syncthreads();
  if (threadIdx.x == 0)
    partial[bid] = wsum[0] + wsum[1] + wsum[2] + wsum[3];
}

// Kernel 2: 256 threads. Thread t loads float4 partial[4t..4t+3] (batch t>>2),
// quad-shuffle to batch sums, normalize on quad leaders, block-reduce.
__global__ __launch_bounds__(BLK) void rank_final_kernel(
    const float* __restrict__ partial,
    const int* __restrict__ lens,
    float* __restrict__ out,
    int B) {
  const int t = threadIdx.x;
  float s = 0.0f;
  if (t * 4 < B * 16) {
    float4 a = ((const float4*)partial)[t];
    s = (a.x + a.y) + (a.z + a.w);
  }
  s += __shfl_xor(s, 1, 64);
  s += __shfl_xor(s, 2, 64);   // all 4 lanes of quad hold batch sum

  float norm = 0.0f, sents = 0.0f;
  if ((t & 3) == 0 && (t >> 2) < B) {
    const int bb = t >> 2;
    const int ln = lens[bb];
    const float len = (float)ln;
    norm = s / (len * len);
    sents = (ln != 0) ? 1.0f : 0.0f;
  }
  for (int off = 32; off > 0; off >>= 1) {
    norm  += __shfl_down(norm, off, 64);
    sents += __shfl_down(sents, off, 64);
  }
  __shared__ float wn[BLK / 64], ws2[BLK / 64];
  if ((t & 63) == 0) { wn[t >> 6] = norm; ws2[t >> 6] = sents; }
  __syncthreads();
  if (t == 0) {
    float N  = (wn[0] + wn[1]) + (wn[2] + wn[3]);
    float Sn = (ws2[0] + ws2[1]) + (ws2[2] + ws2[3]);
    out[0] = N / Sn;
    out[1] = Sn;
  }
}

extern "C" void kernel_launch(void* const* d_in, const int* in_sizes, int n_in,
                              void* d_out, int out_size, void* d_ws, size_t ws_size,
                              hipStream_t stream) {
  const float* preds  = (const float*)d_in[0];
  const float* labels = (const float*)d_in[1];
  const int*   lens   = (const int*)d_in[2];
  float* out = (float*)d_out;

  const int B = in_sizes[2];                  // 64
  float* partial = (float*)d_ws;              // B * 16 floats

  rank_partial_kernel<<<dim3(B * 16), dim3(BLK), 0, stream>>>(preds, labels, partial);
  rank_final_kernel<<<dim3(1), dim3(BLK), 0, stream>>>(partial, lens, out, B);
}